// Round 5
// baseline (1986.581 us; speedup 1.0000x reference)
//
#include <hip/hip_runtime.h>
#include <math.h>

#define H_   8
#define DIN  128
#define DK   16
#define DV   16
#define DE   128
#define B_   128
#define N_   256
#define NORMC 0.25f
#define MAXSEG 304   // hard bound: <=16 L1 knots + <=272 L2 knots -> <=289 segments

// ---------------------------------------------------------------------------
// Kernel 0: extract the edge-MLP (scalar -> 8 heads) as an exact piecewise-
// linear table. One wave. Output: nk knots (sorted), nk+1 segments with
// per-head slope A[8] and intercept B[8] (16 floats per segment).
// ---------------------------------------------------------------------------
__global__ void edge_precompute(
    const float* __restrict__ mw1, const float* __restrict__ mb1,
    const float* __restrict__ mw2, const float* __restrict__ mb2,
    const float* __restrict__ mw3, const float* __restrict__ mb3,
    float* __restrict__ knots_out, float* __restrict__ tab_out,
    int* __restrict__ nk_out) {
  const int t = threadIdx.x;  // 64 threads
  __shared__ float w1[16], b1[16], w2[256], b2[16], w3[128], b3[8];
  __shared__ float k1[16];
  __shared__ float allk[MAXSEG];
  __shared__ float skn[MAXSEG];
  __shared__ int n1s, nks;

  if (t < 16) { w1[t] = mw1[t]; b1[t] = mb1[t]; b2[t] = mb2[t]; }
  if (t < 8) b3[t] = mb3[t];
  for (int x = t; x < 256; x += 64) w2[x] = mw2[x];
  for (int x = t; x < 128; x += 64) w3[x] = mw3[x];
  __syncthreads();

  // Step 1: layer-1 knots, sorted (serial on lane 0; tiny).
  if (t == 0) {
    int n = 0;
    for (int a = 0; a < 16; ++a)
      if (w1[a] != 0.f) k1[n++] = -b1[a] / w1[a];
    for (int x = 1; x < n; ++x) {
      float v = k1[x]; int y = x - 1;
      while (y >= 0 && k1[y] > v) { k1[y + 1] = k1[y]; --y; }
      k1[y + 1] = v;
    }
    n1s = n; nks = 0;
  }
  __syncthreads();
  const int n1 = n1s;

  // Step 2: layer-2 zero crossings inside each layer-1 interval.
  if (t <= n1) {
    const float lo = (t == 0) ? -INFINITY : k1[t - 1];
    const float hi = (t == n1) ? INFINITY : k1[t];
    float xm;
    if (n1 == 0) xm = 0.f;
    else if (t == 0) xm = k1[0] - 1.f;
    else if (t == n1) xm = k1[n1 - 1] + 1.f;
    else xm = 0.5f * (lo + hi);
#pragma unroll
    for (int c = 0; c < 16; ++c) {
      float alpha = 0.f, beta = b2[c];
#pragma unroll
      for (int a = 0; a < 16; ++a) {
        const float u = w1[a] * xm + b1[a];
        const float g = (u > 0.f) ? 1.f : 0.f;
        alpha += g * w1[a] * w2[a * 16 + c];
        beta  += g * b1[a] * w2[a * 16 + c];
      }
      if (alpha != 0.f) {
        const float z = -beta / alpha;
        if (z > lo && z < hi) { int p = atomicAdd(&nks, 1); allk[p] = z; }
      }
    }
  }
  if (t < n1) { int p = atomicAdd(&nks, 1); allk[p] = k1[t]; }
  __syncthreads();
  const int nk = nks;

  // Step 3: rank sort (<=288 elements).
  for (int x = t; x < nk; x += 64) {
    const float v = allk[x];
    int r = 0;
    for (int y = 0; y < nk; ++y) {
      const float u = allk[y];
      r += (u < v) || (u == v && y < x);
    }
    skn[r] = v;
  }
  __syncthreads();

  // Step 4: per-segment exact linear form for all 8 heads.
  for (int s = t; s <= nk; s += 64) {
    float xm;
    if (nk == 0) xm = 0.f;
    else if (s == 0) xm = skn[0] - 1.f;
    else if (s == nk) xm = skn[nk - 1] + 1.f;
    else xm = 0.5f * (skn[s - 1] + skn[s]);
    float alpha[16], beta[16];
#pragma unroll
    for (int c = 0; c < 16; ++c) {
      float al = 0.f, be = b2[c];
#pragma unroll
      for (int a = 0; a < 16; ++a) {
        const float u = w1[a] * xm + b1[a];
        const float g = (u > 0.f) ? 1.f : 0.f;
        al += g * w1[a] * w2[a * 16 + c];
        be += g * b1[a] * w2[a * 16 + c];
      }
      alpha[c] = al; beta[c] = be;
    }
    float Ah[8], Bh[8];
#pragma unroll
    for (int h = 0; h < 8; ++h) { Ah[h] = 0.f; Bh[h] = b3[h]; }
#pragma unroll
    for (int c = 0; c < 16; ++c) {
      const float argc = alpha[c] * xm + beta[c];
      if (argc > 0.f) {
#pragma unroll
        for (int h = 0; h < 8; ++h) {
          Ah[h] += alpha[c] * w3[c * 8 + h];
          Bh[h] += beta[c]  * w3[c * 8 + h];
        }
      }
    }
#pragma unroll
    for (int h = 0; h < 8; ++h) {
      tab_out[s * 16 + h]     = Ah[h];
      tab_out[s * 16 + 8 + h] = Bh[h];
    }
  }
  for (int x = t; x < nk; x += 64) knots_out[x] = skn[x];
  if (t == 0) nk_out[0] = nk;
}

// ---------------------------------------------------------------------------
// Kernel 1: Q/K/V projections. grid (64, 8), block 256, 2 rows/thread.
// XCD swizzle: the 8 head-blocks reading the same input rows become
// consecutive on one XCD (L2 reuse of q/h rows).
// ---------------------------------------------------------------------------
__global__ __launch_bounds__(256) void qkv_kernel(
    const float* __restrict__ qin, const float* __restrict__ hin,
    const float* __restrict__ Wq, const float* __restrict__ Wk,
    const float* __restrict__ Wv, float* __restrict__ Q,
    float* __restrict__ K, float* __restrict__ V) {
  const int lin = blockIdx.y * 64 + blockIdx.x;   // HW linear id (gridDim.x=64)
  const int swz = (lin & 7) * 64 + (lin >> 3);    // XCD c owns [c*64,(c+1)*64)
  const int hd = swz & 7;
  const int xb = swz >> 3;
  const int r0 = xb * 512 + threadIdx.x;          // rows r0 and r0+256
  __shared__ __align__(16) float wt[3][16][128];  // [mat][k][d]

  {
    const float* W;
#pragma unroll
    for (int m = 0; m < 3; ++m) {
      W = (m == 0) ? Wq : (m == 1) ? Wk : Wv;
      for (int idx = threadIdx.x; idx < 2048; idx += 256) {
        const int d = idx >> 4, k = idx & 15;
        wt[m][k][d] = W[hd * 2048 + idx];
      }
    }
  }
  __syncthreads();

  for (int m = 0; m < 3; ++m) {
    const float* src = (m == 0) ? qin : hin;
    float acc0[16], acc1[16];
#pragma unroll
    for (int k = 0; k < 16; ++k) { acc0[k] = 0.f; acc1[k] = 0.f; }
    const float4* row0 = reinterpret_cast<const float4*>(src + (size_t)r0 * DIN);
    const float4* row1 = reinterpret_cast<const float4*>(src + (size_t)(r0 + 256) * DIN);
    for (int d4 = 0; d4 < 32; ++d4) {
      const float4 c0 = row0[d4];
      const float4 c1 = row1[d4];
#pragma unroll
      for (int k = 0; k < 16; ++k) {
        const float4 w = *reinterpret_cast<const float4*>(&wt[m][k][d4 * 4]);
        acc0[k] += c0.x * w.x + c0.y * w.y + c0.z * w.z + c0.w * w.w;
        acc1[k] += c1.x * w.x + c1.y * w.y + c1.z * w.z + c1.w * w.w;
      }
    }
    const float scale = (m == 0) ? NORMC : 1.f;
    float* dst = (m == 0) ? Q : (m == 1) ? K : V;
    float4* o0 = reinterpret_cast<float4*>(dst + ((size_t)hd * B_ * N_ + r0) * DK);
    float4* o1 = reinterpret_cast<float4*>(dst + ((size_t)hd * B_ * N_ + r0 + 256) * DK);
#pragma unroll
    for (int kq = 0; kq < 4; ++kq) {
      o0[kq] = make_float4(acc0[kq*4+0]*scale, acc0[kq*4+1]*scale,
                           acc0[kq*4+2]*scale, acc0[kq*4+3]*scale);
      o1[kq] = make_float4(acc1[kq*4+0]*scale, acc1[kq*4+1]*scale,
                           acc1[kq*4+2]*scale, acc1[kq*4+3]*scale);
    }
  }
}

// ---------------------------------------------------------------------------
// Kernel 2: fused bias-lookup + masked softmax attention + output projection.
// grid = B*N blocks, block = 256 (thread = key j). XCD swizzle: XCD c owns
// b in [16c, 16c+16); the 256 i-blocks sharing K/V[b] run back-to-back on
// one XCD so K/V, edge/mask rows, and the segment table stay L2-resident.
// ---------------------------------------------------------------------------
__global__ __launch_bounds__(256, 4) void attn_kernel(
    const float* __restrict__ Q, const float* __restrict__ K,
    const float* __restrict__ V, const int* __restrict__ mask,
    const float* __restrict__ edge, const float* __restrict__ knots_g,
    const float* __restrict__ tab_g, const int* __restrict__ nk_g,
    const float* __restrict__ Wo, float* __restrict__ out) {
  const int t = threadIdx.x;
  const int lin = blockIdx.x;
  const int swz = (lin & 7) * 4096 + (lin >> 3);  // bijective: 32768 = 8*4096
  const int b = swz >> 8;
  const int i = swz & 255;

  __shared__ __align__(16) float skn[MAXSEG];
  __shared__ __align__(16) float stab[MAXSEG * 16];
  __shared__ float qi[H_ * DK];
  __shared__ float P[H_][N_];
  __shared__ float redmax[H_][4];
  __shared__ float redsum[H_][4];
  __shared__ float sumrcp[H_];
  __shared__ __align__(16) float4 part[H_][4][8];
  __shared__ __align__(16) float heads[H_ * DV];

  const int NK = nk_g[0];
  for (int x = t; x < NK; x += 256) skn[x] = knots_g[x];
  {
    const int nv4 = (NK + 1) * 4;  // table is 16 floats/segment -> 4 float4s
    const float4* tg4 = reinterpret_cast<const float4*>(tab_g);
    float4* st4 = reinterpret_cast<float4*>(stab);
    for (int x = t; x < nv4; x += 256) st4[x] = tg4[x];
  }
  if (t < H_ * DK)
    qi[t] = Q[((size_t)(t >> 4) * B_ * N_ + (size_t)b * N_ + i) * DK + (t & 15)];
  __syncthreads();

  // ---- Phase 1: bias via pw-linear table + QK score, key j = t ------------
  const int j = t;
  const size_t rowij = (size_t)(b * N_ + i) * N_ + j;
  const int mv = mask[rowij];
  const float e = edge[rowij];

  int lo = 0, hi = NK;
  while (lo < hi) {
    const int mid = (lo + hi) >> 1;
    const bool lt = skn[mid] < e;
    lo = lt ? mid + 1 : lo;
    hi = lt ? hi : mid;
  }
  const float4 ta = *reinterpret_cast<const float4*>(&stab[lo * 16]);
  const float4 tb = *reinterpret_cast<const float4*>(&stab[lo * 16 + 4]);
  const float4 tc = *reinterpret_cast<const float4*>(&stab[lo * 16 + 8]);
  const float4 td = *reinterpret_cast<const float4*>(&stab[lo * 16 + 12]);
  float s[H_];
  s[0] = fmaf(ta.x, e, tc.x); s[1] = fmaf(ta.y, e, tc.y);
  s[2] = fmaf(ta.z, e, tc.z); s[3] = fmaf(ta.w, e, tc.w);
  s[4] = fmaf(tb.x, e, td.x); s[5] = fmaf(tb.y, e, td.y);
  s[6] = fmaf(tb.z, e, td.z); s[7] = fmaf(tb.w, e, td.w);

  const float4* Kp = reinterpret_cast<const float4*>(K);
#pragma unroll
  for (int hh = 0; hh < H_; ++hh) {
    const size_t kb = ((size_t)hh * B_ * N_ + (size_t)b * N_ + j) * (DK / 4);
    const float4 k0 = Kp[kb + 0], k1 = Kp[kb + 1], k2 = Kp[kb + 2], k3 = Kp[kb + 3];
    const float* qh = &qi[hh * DK];   // Q pre-scaled by NORMC
    const float dot =
        qh[0] * k0.x + qh[1] * k0.y + qh[2] * k0.z + qh[3] * k0.w +
        qh[4] * k1.x + qh[5] * k1.y + qh[6] * k1.z + qh[7] * k1.w +
        qh[8] * k2.x + qh[9] * k2.y + qh[10] * k2.z + qh[11] * k2.w +
        qh[12] * k3.x + qh[13] * k3.y + qh[14] * k3.z + qh[15] * k3.w;
    s[hh] += dot;
    if (mv) s[hh] = -INFINITY;
  }

  // ---- Softmax (P left unnormalized; one reciprocal per head) -------------
#pragma unroll
  for (int hh = 0; hh < H_; ++hh) {
    float m = s[hh];
    for (int off = 32; off > 0; off >>= 1) m = fmaxf(m, __shfl_down(m, off, 64));
    if ((t & 63) == 0) redmax[hh][t >> 6] = m;
  }
  __syncthreads();
  float p[H_];
#pragma unroll
  for (int hh = 0; hh < H_; ++hh) {
    const float m = fmaxf(fmaxf(redmax[hh][0], redmax[hh][1]),
                          fmaxf(redmax[hh][2], redmax[hh][3]));
    float pv = (mv || m == -INFINITY) ? 0.f : __expf(s[hh] - m);
    p[hh] = pv;
    float sum = pv;
    for (int off = 32; off > 0; off >>= 1) sum += __shfl_down(sum, off, 64);
    if ((t & 63) == 0) redsum[hh][t >> 6] = sum;
  }
  __syncthreads();
#pragma unroll
  for (int hh = 0; hh < H_; ++hh) {
    P[hh][j] = p[hh];
    if (t == 0) {
      const float sum = redsum[hh][0] + redsum[hh][1] + redsum[hh][2] + redsum[hh][3];
      sumrcp[hh] = (sum > 0.f) ? 1.f / sum : 0.f;
    }
  }
  __syncthreads();

  // ---- Phase 2: heads[h,:] = (1/sum_h) * sum_j P[h,j] * V[h,b,j,:] --------
  {
    const int h2 = t >> 5;
    const int g = t & 31;
    const int v4 = g & 3;
    const int jsl = g >> 2;
    const float4* Vp = reinterpret_cast<const float4*>(V);
    const size_t vbase = ((size_t)h2 * B_ * N_ + (size_t)b * N_) * 4;
    float4 acc = make_float4(0.f, 0.f, 0.f, 0.f);
    for (int jj = 0; jj < 32; ++jj) {
      const int jx = jj * 8 + jsl;
      const float pj = P[h2][jx];
      const float4 vv = Vp[vbase + (size_t)jx * 4 + v4];
      acc.x = fmaf(pj, vv.x, acc.x);
      acc.y = fmaf(pj, vv.y, acc.y);
      acc.z = fmaf(pj, vv.z, acc.z);
      acc.w = fmaf(pj, vv.w, acc.w);
    }
    part[h2][v4][jsl] = acc;
  }
  __syncthreads();
  if (t < 32) {
    const int hh = t >> 2, vq = t & 3;
    float4 sacc = part[hh][vq][0];
#pragma unroll
    for (int r = 1; r < 8; ++r) {
      const float4 pz = part[hh][vq][r];
      sacc.x += pz.x; sacc.y += pz.y; sacc.z += pz.z; sacc.w += pz.w;
    }
    const float rs = sumrcp[hh];
    heads[hh * DV + vq * 4 + 0] = sacc.x * rs;
    heads[hh * DV + vq * 4 + 1] = sacc.y * rs;
    heads[hh * DV + vq * 4 + 2] = sacc.z * rs;
    heads[hh * DV + vq * 4 + 3] = sacc.w * rs;
  }
  __syncthreads();

  // ---- Phase 3: out[b,i,e] = sum_{hv} heads[hv] * Wo[hv,e] ----------------
  if (t < DE) {
    float acc = 0.f;
#pragma unroll
    for (int hq = 0; hq < 32; ++hq) {
      const float4 hv4 = *reinterpret_cast<const float4*>(&heads[hq * 4]);
      acc = fmaf(hv4.x, Wo[(hq * 4 + 0) * DE + t], acc);
      acc = fmaf(hv4.y, Wo[(hq * 4 + 1) * DE + t], acc);
      acc = fmaf(hv4.z, Wo[(hq * 4 + 2) * DE + t], acc);
      acc = fmaf(hv4.w, Wo[(hq * 4 + 3) * DE + t], acc);
    }
    out[((size_t)(b * N_ + i)) * DE + t] = acc;
  }
}

extern "C" void kernel_launch(void* const* d_in, const int* in_sizes, int n_in,
                              void* d_out, int out_size, void* d_ws, size_t ws_size,
                              hipStream_t stream) {
  const float* q    = (const float*)d_in[0];
  const float* hm   = (const float*)d_in[1];
  const int* mask   = (const int*)d_in[2];
  const float* edge = (const float*)d_in[3];
  const float* Wq   = (const float*)d_in[4];
  const float* Wk   = (const float*)d_in[5];
  const float* Wv   = (const float*)d_in[6];
  const float* Wo   = (const float*)d_in[7];
  const float* mw1  = (const float*)d_in[8];
  const float* mb1  = (const float*)d_in[9];
  const float* mw2  = (const float*)d_in[10];
  const float* mb2  = (const float*)d_in[11];
  const float* mw3  = (const float*)d_in[12];
  const float* mb3  = (const float*)d_in[13];
  float* out = (float*)d_out;

  float* ws = (float*)d_ws;
  const size_t per = (size_t)H_ * B_ * N_ * DK;  // 4,194,304 floats
  float* Q = ws;
  float* K = ws + per;
  float* V = ws + 2 * per;
  float* knots = ws + 3 * per;          // 512 slots
  float* tab   = knots + 512;           // MAXSEG*16 <= 4864 floats -> 8192 slots
  int*   nk    = (int*)(tab + 8192);

  edge_precompute<<<1, 64, 0, stream>>>(mw1, mb1, mw2, mb2, mw3, mb3, knots, tab, nk);
  qkv_kernel<<<dim3(B_ * N_ / 512, H_), 256, 0, stream>>>(q, hm, Wq, Wk, Wv, Q, K, V);
  attn_kernel<<<dim3(B_ * N_), 256, 0, stream>>>(Q, K, V, mask, edge, knots, tab, nk,
                                                 Wo, out);
}

// Round 7
// 1039.879 us; speedup vs baseline: 1.9104x; 1.9104x over previous
//
#include <hip/hip_runtime.h>
#include <math.h>

#define H_   8
#define DIN  128
#define DK   16
#define DV   16
#define DE   128
#define B_   128
#define N_   256
#define NORMC 0.25f
#define MAXSEG 304   // hard bound: <=16 L1 knots + <=272 L2 knots -> <=289 segments

// ---------------------------------------------------------------------------
// Kernel 0: extract the edge-MLP (scalar -> 8 heads) as an exact piecewise-
// linear table. One wave. Output: nk knots (sorted), nk+1 segments with
// per-head slope A[8] and intercept B[8] (16 floats per segment).
// ---------------------------------------------------------------------------
__global__ void edge_precompute(
    const float* __restrict__ mw1, const float* __restrict__ mb1,
    const float* __restrict__ mw2, const float* __restrict__ mb2,
    const float* __restrict__ mw3, const float* __restrict__ mb3,
    float* __restrict__ knots_out, float* __restrict__ tab_out,
    int* __restrict__ nk_out) {
  const int t = threadIdx.x;  // 64 threads
  __shared__ float w1[16], b1[16], w2[256], b2[16], w3[128], b3[8];
  __shared__ float k1[16];
  __shared__ float allk[MAXSEG];
  __shared__ float skn[MAXSEG];
  __shared__ int n1s, nks;

  if (t < 16) { w1[t] = mw1[t]; b1[t] = mb1[t]; b2[t] = mb2[t]; }
  if (t < 8) b3[t] = mb3[t];
  for (int x = t; x < 256; x += 64) w2[x] = mw2[x];
  for (int x = t; x < 128; x += 64) w3[x] = mw3[x];
  __syncthreads();

  // Step 1: layer-1 knots, sorted (serial on lane 0; tiny).
  if (t == 0) {
    int n = 0;
    for (int a = 0; a < 16; ++a)
      if (w1[a] != 0.f) k1[n++] = -b1[a] / w1[a];
    for (int x = 1; x < n; ++x) {
      float v = k1[x]; int y = x - 1;
      while (y >= 0 && k1[y] > v) { k1[y + 1] = k1[y]; --y; }
      k1[y + 1] = v;
    }
    n1s = n; nks = 0;
  }
  __syncthreads();
  const int n1 = n1s;

  // Step 2: layer-2 zero crossings inside each layer-1 interval.
  if (t <= n1) {
    const float lo = (t == 0) ? -INFINITY : k1[t - 1];
    const float hi = (t == n1) ? INFINITY : k1[t];
    float xm;
    if (n1 == 0) xm = 0.f;
    else if (t == 0) xm = k1[0] - 1.f;
    else if (t == n1) xm = k1[n1 - 1] + 1.f;
    else xm = 0.5f * (lo + hi);
#pragma unroll
    for (int c = 0; c < 16; ++c) {
      float alpha = 0.f, beta = b2[c];
#pragma unroll
      for (int a = 0; a < 16; ++a) {
        const float u = w1[a] * xm + b1[a];
        const float g = (u > 0.f) ? 1.f : 0.f;
        alpha += g * w1[a] * w2[a * 16 + c];
        beta  += g * b1[a] * w2[a * 16 + c];
      }
      if (alpha != 0.f) {
        const float z = -beta / alpha;
        if (z > lo && z < hi) { int p = atomicAdd(&nks, 1); allk[p] = z; }
      }
    }
  }
  if (t < n1) { int p = atomicAdd(&nks, 1); allk[p] = k1[t]; }
  __syncthreads();
  const int nk = nks;

  // Step 3: rank sort (<=288 elements).
  for (int x = t; x < nk; x += 64) {
    const float v = allk[x];
    int r = 0;
    for (int y = 0; y < nk; ++y) {
      const float u = allk[y];
      r += (u < v) || (u == v && y < x);
    }
    skn[r] = v;
  }
  __syncthreads();

  // Step 4: per-segment exact linear form for all 8 heads.
  for (int s = t; s <= nk; s += 64) {
    float xm;
    if (nk == 0) xm = 0.f;
    else if (s == 0) xm = skn[0] - 1.f;
    else if (s == nk) xm = skn[nk - 1] + 1.f;
    else xm = 0.5f * (skn[s - 1] + skn[s]);
    float alpha[16], beta[16];
#pragma unroll
    for (int c = 0; c < 16; ++c) {
      float al = 0.f, be = b2[c];
#pragma unroll
      for (int a = 0; a < 16; ++a) {
        const float u = w1[a] * xm + b1[a];
        const float g = (u > 0.f) ? 1.f : 0.f;
        al += g * w1[a] * w2[a * 16 + c];
        be += g * b1[a] * w2[a * 16 + c];
      }
      alpha[c] = al; beta[c] = be;
    }
    float Ah[8], Bh[8];
#pragma unroll
    for (int h = 0; h < 8; ++h) { Ah[h] = 0.f; Bh[h] = b3[h]; }
#pragma unroll
    for (int c = 0; c < 16; ++c) {
      const float argc = alpha[c] * xm + beta[c];
      if (argc > 0.f) {
#pragma unroll
        for (int h = 0; h < 8; ++h) {
          Ah[h] += alpha[c] * w3[c * 8 + h];
          Bh[h] += beta[c]  * w3[c * 8 + h];
        }
      }
    }
#pragma unroll
    for (int h = 0; h < 8; ++h) {
      tab_out[s * 16 + h]     = Ah[h];
      tab_out[s * 16 + 8 + h] = Bh[h];
    }
  }
  for (int x = t; x < nk; x += 64) knots_out[x] = skn[x];
  if (t == 0) nk_out[0] = nk;
}

// ---------------------------------------------------------------------------
// Kernel 1: Q/K/V projections. grid (64, 8), block 256, 2 rows/thread.
// XCD swizzle: the 8 head-blocks reading the same input rows become
// consecutive on one XCD (L2 reuse of q/h rows).
// ---------------------------------------------------------------------------
__global__ __launch_bounds__(256) void qkv_kernel(
    const float* __restrict__ qin, const float* __restrict__ hin,
    const float* __restrict__ Wq, const float* __restrict__ Wk,
    const float* __restrict__ Wv, float* __restrict__ Q,
    float* __restrict__ K, float* __restrict__ V) {
  const int lin = blockIdx.y * 64 + blockIdx.x;   // HW linear id (gridDim.x=64)
  const int swz = (lin & 7) * 64 + (lin >> 3);    // XCD c owns [c*64,(c+1)*64)
  const int hd = swz & 7;
  const int xb = swz >> 3;
  const int r0 = xb * 512 + threadIdx.x;          // rows r0 and r0+256
  __shared__ __align__(16) float wt[3][16][128];  // [mat][k][d]

  {
    const float* W;
#pragma unroll
    for (int m = 0; m < 3; ++m) {
      W = (m == 0) ? Wq : (m == 1) ? Wk : Wv;
      for (int idx = threadIdx.x; idx < 2048; idx += 256) {
        const int d = idx >> 4, k = idx & 15;
        wt[m][k][d] = W[hd * 2048 + idx];
      }
    }
  }
  __syncthreads();

  for (int m = 0; m < 3; ++m) {
    const float* src = (m == 0) ? qin : hin;
    float acc0[16], acc1[16];
#pragma unroll
    for (int k = 0; k < 16; ++k) { acc0[k] = 0.f; acc1[k] = 0.f; }
    const float4* row0 = reinterpret_cast<const float4*>(src + (size_t)r0 * DIN);
    const float4* row1 = reinterpret_cast<const float4*>(src + (size_t)(r0 + 256) * DIN);
    for (int d4 = 0; d4 < 32; ++d4) {
      const float4 c0 = row0[d4];
      const float4 c1 = row1[d4];
#pragma unroll
      for (int k = 0; k < 16; ++k) {
        const float4 w = *reinterpret_cast<const float4*>(&wt[m][k][d4 * 4]);
        acc0[k] += c0.x * w.x + c0.y * w.y + c0.z * w.z + c0.w * w.w;
        acc1[k] += c1.x * w.x + c1.y * w.y + c1.z * w.z + c1.w * w.w;
      }
    }
    const float scale = (m == 0) ? NORMC : 1.f;
    float* dst = (m == 0) ? Q : (m == 1) ? K : V;
    float4* o0 = reinterpret_cast<float4*>(dst + ((size_t)hd * B_ * N_ + r0) * DK);
    float4* o1 = reinterpret_cast<float4*>(dst + ((size_t)hd * B_ * N_ + r0 + 256) * DK);
#pragma unroll
    for (int kq = 0; kq < 4; ++kq) {
      o0[kq] = make_float4(acc0[kq*4+0]*scale, acc0[kq*4+1]*scale,
                           acc0[kq*4+2]*scale, acc0[kq*4+3]*scale);
      o1[kq] = make_float4(acc1[kq*4+0]*scale, acc1[kq*4+1]*scale,
                           acc1[kq*4+2]*scale, acc1[kq*4+3]*scale);
    }
  }
}

// ---------------------------------------------------------------------------
// Kernel 2: fused bias-lookup + masked softmax attention + output projection.
// grid = B*N blocks, block = 256 (thread = key j). XCD swizzle keeps same-b
// blocks on one XCD. NOTE: no min-waves clause in launch_bounds — occupancy
// is LDS-bound at 4 blocks/CU anyway, and forcing a VGPR cap caused 4 GiB of
// scratch-spill HBM traffic (rounds 4/5).
// ---------------------------------------------------------------------------
__global__ __launch_bounds__(256) void attn_kernel(
    const float* __restrict__ Q, const float* __restrict__ K,
    const float* __restrict__ V, const int* __restrict__ mask,
    const float* __restrict__ edge, const float* __restrict__ knots_g,
    const float* __restrict__ tab_g, const int* __restrict__ nk_g,
    const float* __restrict__ Wo, float* __restrict__ out) {
  const int t = threadIdx.x;
  const int lin = blockIdx.x;
  const int swz = (lin & 7) * 4096 + (lin >> 3);  // bijective: 32768 = 8*4096
  const int b = swz >> 8;
  const int i = swz & 255;

  __shared__ __align__(16) float skn[MAXSEG];
  __shared__ __align__(16) float stab[MAXSEG * 16];
  __shared__ float qi[H_ * DK];
  __shared__ float P[H_][N_];
  __shared__ float redmax[H_][4];
  __shared__ float redsum[H_][4];
  __shared__ float sumrcp[H_];
  __shared__ __align__(16) float4 part[H_][4][8];
  __shared__ __align__(16) float heads[H_ * DV];

  const int NK = nk_g[0];
  for (int x = t; x < NK; x += 256) skn[x] = knots_g[x];
  {
    const int nv4 = (NK + 1) * 4;  // table is 16 floats/segment -> 4 float4s
    const float4* tg4 = reinterpret_cast<const float4*>(tab_g);
    float4* st4 = reinterpret_cast<float4*>(stab);
    for (int x = t; x < nv4; x += 256) st4[x] = tg4[x];
  }
  if (t < H_ * DK)
    qi[t] = Q[((size_t)(t >> 4) * B_ * N_ + (size_t)b * N_ + i) * DK + (t & 15)];
  __syncthreads();

  // ---- Phase 1: bias via pw-linear table + QK score, key j = t ------------
  const int j = t;
  const size_t rowij = (size_t)(b * N_ + i) * N_ + j;
  const int mv = mask[rowij];
  const float e = edge[rowij];

  int lo = 0, hi = NK;
  while (lo < hi) {
    const int mid = (lo + hi) >> 1;
    const bool lt = skn[mid] < e;
    lo = lt ? mid + 1 : lo;
    hi = lt ? hi : mid;
  }
  const float4 ta = *reinterpret_cast<const float4*>(&stab[lo * 16]);
  const float4 tb = *reinterpret_cast<const float4*>(&stab[lo * 16 + 4]);
  const float4 tc = *reinterpret_cast<const float4*>(&stab[lo * 16 + 8]);
  const float4 td = *reinterpret_cast<const float4*>(&stab[lo * 16 + 12]);
  float s[H_];
  s[0] = fmaf(ta.x, e, tc.x); s[1] = fmaf(ta.y, e, tc.y);
  s[2] = fmaf(ta.z, e, tc.z); s[3] = fmaf(ta.w, e, tc.w);
  s[4] = fmaf(tb.x, e, td.x); s[5] = fmaf(tb.y, e, td.y);
  s[6] = fmaf(tb.z, e, td.z); s[7] = fmaf(tb.w, e, td.w);

  const float4* Kp = reinterpret_cast<const float4*>(K);
#pragma unroll
  for (int hh = 0; hh < H_; ++hh) {
    const size_t kb = ((size_t)hh * B_ * N_ + (size_t)b * N_ + j) * (DK / 4);
    const float4 k0 = Kp[kb + 0], k1 = Kp[kb + 1], k2 = Kp[kb + 2], k3 = Kp[kb + 3];
    const float* qh = &qi[hh * DK];   // Q pre-scaled by NORMC
    const float dot =
        qh[0] * k0.x + qh[1] * k0.y + qh[2] * k0.z + qh[3] * k0.w +
        qh[4] * k1.x + qh[5] * k1.y + qh[6] * k1.z + qh[7] * k1.w +
        qh[8] * k2.x + qh[9] * k2.y + qh[10] * k2.z + qh[11] * k2.w +
        qh[12] * k3.x + qh[13] * k3.y + qh[14] * k3.z + qh[15] * k3.w;
    s[hh] += dot;
    if (mv) s[hh] = -INFINITY;
  }

  // ---- Softmax (P left unnormalized; one reciprocal per head) -------------
#pragma unroll
  for (int hh = 0; hh < H_; ++hh) {
    float m = s[hh];
    for (int off = 32; off > 0; off >>= 1) m = fmaxf(m, __shfl_down(m, off, 64));
    if ((t & 63) == 0) redmax[hh][t >> 6] = m;
  }
  __syncthreads();
  float p[H_];
#pragma unroll
  for (int hh = 0; hh < H_; ++hh) {
    const float m = fmaxf(fmaxf(redmax[hh][0], redmax[hh][1]),
                          fmaxf(redmax[hh][2], redmax[hh][3]));
    float pv = (mv || m == -INFINITY) ? 0.f : __expf(s[hh] - m);
    p[hh] = pv;
    float sum = pv;
    for (int off = 32; off > 0; off >>= 1) sum += __shfl_down(sum, off, 64);
    if ((t & 63) == 0) redsum[hh][t >> 6] = sum;
  }
  __syncthreads();
#pragma unroll
  for (int hh = 0; hh < H_; ++hh) {
    P[hh][j] = p[hh];
    if (t == 0) {
      const float sum = redsum[hh][0] + redsum[hh][1] + redsum[hh][2] + redsum[hh][3];
      sumrcp[hh] = (sum > 0.f) ? 1.f / sum : 0.f;
    }
  }
  __syncthreads();

  // ---- Phase 2: heads[h,:] = (1/sum_h) * sum_j P[h,j] * V[h,b,j,:] --------
  {
    const int h2 = t >> 5;
    const int g = t & 31;
    const int v4 = g & 3;
    const int jsl = g >> 2;
    const float4* Vp = reinterpret_cast<const float4*>(V);
    const size_t vbase = ((size_t)h2 * B_ * N_ + (size_t)b * N_) * 4;
    float4 acc = make_float4(0.f, 0.f, 0.f, 0.f);
    for (int jj = 0; jj < 32; ++jj) {
      const int jx = jj * 8 + jsl;
      const float pj = P[h2][jx];
      const float4 vv = Vp[vbase + (size_t)jx * 4 + v4];
      acc.x = fmaf(pj, vv.x, acc.x);
      acc.y = fmaf(pj, vv.y, acc.y);
      acc.z = fmaf(pj, vv.z, acc.z);
      acc.w = fmaf(pj, vv.w, acc.w);
    }
    part[h2][v4][jsl] = acc;
  }
  __syncthreads();
  if (t < 32) {
    const int hh = t >> 2, vq = t & 3;
    float4 sacc = part[hh][vq][0];
#pragma unroll
    for (int r = 1; r < 8; ++r) {
      const float4 pz = part[hh][vq][r];
      sacc.x += pz.x; sacc.y += pz.y; sacc.z += pz.z; sacc.w += pz.w;
    }
    const float rs = sumrcp[hh];
    heads[hh * DV + vq * 4 + 0] = sacc.x * rs;
    heads[hh * DV + vq * 4 + 1] = sacc.y * rs;
    heads[hh * DV + vq * 4 + 2] = sacc.z * rs;
    heads[hh * DV + vq * 4 + 3] = sacc.w * rs;
  }
  __syncthreads();

  // ---- Phase 3: out[b,i,e] = sum_{hv} heads[hv] * Wo[hv,e] ----------------
  if (t < DE) {
    float acc = 0.f;
#pragma unroll
    for (int hq = 0; hq < 32; ++hq) {
      const float4 hv4 = *reinterpret_cast<const float4*>(&heads[hq * 4]);
      acc = fmaf(hv4.x, Wo[(hq * 4 + 0) * DE + t], acc);
      acc = fmaf(hv4.y, Wo[(hq * 4 + 1) * DE + t], acc);
      acc = fmaf(hv4.z, Wo[(hq * 4 + 2) * DE + t], acc);
      acc = fmaf(hv4.w, Wo[(hq * 4 + 3) * DE + t], acc);
    }
    out[((size_t)(b * N_ + i)) * DE + t] = acc;
  }
}

extern "C" void kernel_launch(void* const* d_in, const int* in_sizes, int n_in,
                              void* d_out, int out_size, void* d_ws, size_t ws_size,
                              hipStream_t stream) {
  const float* q    = (const float*)d_in[0];
  const float* hm   = (const float*)d_in[1];
  const int* mask   = (const int*)d_in[2];
  const float* edge = (const float*)d_in[3];
  const float* Wq   = (const float*)d_in[4];
  const float* Wk   = (const float*)d_in[5];
  const float* Wv   = (const float*)d_in[6];
  const float* Wo   = (const float*)d_in[7];
  const float* mw1  = (const float*)d_in[8];
  const float* mb1  = (const float*)d_in[9];
  const float* mw2  = (const float*)d_in[10];
  const float* mb2  = (const float*)d_in[11];
  const float* mw3  = (const float*)d_in[12];
  const float* mb3  = (const float*)d_in[13];
  float* out = (float*)d_out;

  float* ws = (float*)d_ws;
  const size_t per = (size_t)H_ * B_ * N_ * DK;  // 4,194,304 floats
  float* Q = ws;
  float* K = ws + per;
  float* V = ws + 2 * per;
  float* knots = ws + 3 * per;          // 512 slots
  float* tab   = knots + 512;           // MAXSEG*16 <= 4864 floats -> 8192 slots
  int*   nk    = (int*)(tab + 8192);

  edge_precompute<<<1, 64, 0, stream>>>(mw1, mb1, mw2, mb2, mw3, mb3, knots, tab, nk);
  qkv_kernel<<<dim3(B_ * N_ / 512, H_), 256, 0, stream>>>(q, hm, Wq, Wk, Wv, Q, K, V);
  attn_kernel<<<dim3(B_ * N_), 256, 0, stream>>>(Q, K, V, mask, edge, knots, tab, nk,
                                                 Wo, out);
}

// Round 9
// 854.549 us; speedup vs baseline: 2.3247x; 1.2169x over previous
//
#include <hip/hip_runtime.h>
#include <math.h>

#define H_   8
#define DIN  128
#define DK   16
#define DV   16
#define DE   128
#define B_   128
#define N_   256
#define NORMC 0.25f
#define MAXSEG 304   // hard bound: <=16 L1 knots + <=272 L2 knots -> <=289 segments
#define LUTN 2048
#define LUT_LO (-16.0f)
#define LUT_SCALE 64.0f   // LUTN bins over [-16,16)
#define PADN 260          // P row pad: 260 mod 32 = 4 -> PV reads <=2-way

// ---------------------------------------------------------------------------
// Kernel 0: extract the edge-MLP (scalar -> 8 heads) as an exact piecewise-
// linear table + a bin->segment LUT. One wave.
// ---------------------------------------------------------------------------
__global__ void edge_precompute(
    const float* __restrict__ mw1, const float* __restrict__ mb1,
    const float* __restrict__ mw2, const float* __restrict__ mb2,
    const float* __restrict__ mw3, const float* __restrict__ mb3,
    float* __restrict__ knots_out, float* __restrict__ tab_out,
    int* __restrict__ nk_out, int* __restrict__ lut_out) {
  const int t = threadIdx.x;  // 64 threads
  __shared__ float w1[16], b1[16], w2[256], b2[16], w3[128], b3[8];
  __shared__ float k1[16];
  __shared__ float allk[MAXSEG];
  __shared__ float skn[MAXSEG];
  __shared__ int n1s, nks;

  if (t < 16) { w1[t] = mw1[t]; b1[t] = mb1[t]; b2[t] = mb2[t]; }
  if (t < 8) b3[t] = mb3[t];
  for (int x = t; x < 256; x += 64) w2[x] = mw2[x];
  for (int x = t; x < 128; x += 64) w3[x] = mw3[x];
  __syncthreads();

  // Step 1: layer-1 knots, sorted (serial on lane 0; tiny).
  if (t == 0) {
    int n = 0;
    for (int a = 0; a < 16; ++a)
      if (w1[a] != 0.f) k1[n++] = -b1[a] / w1[a];
    for (int x = 1; x < n; ++x) {
      float v = k1[x]; int y = x - 1;
      while (y >= 0 && k1[y] > v) { k1[y + 1] = k1[y]; --y; }
      k1[y + 1] = v;
    }
    n1s = n; nks = 0;
  }
  __syncthreads();
  const int n1 = n1s;

  // Step 2: layer-2 zero crossings inside each layer-1 interval.
  if (t <= n1) {
    const float lo = (t == 0) ? -INFINITY : k1[t - 1];
    const float hi = (t == n1) ? INFINITY : k1[t];
    float xm;
    if (n1 == 0) xm = 0.f;
    else if (t == 0) xm = k1[0] - 1.f;
    else if (t == n1) xm = k1[n1 - 1] + 1.f;
    else xm = 0.5f * (lo + hi);
#pragma unroll
    for (int c = 0; c < 16; ++c) {
      float alpha = 0.f, beta = b2[c];
#pragma unroll
      for (int a = 0; a < 16; ++a) {
        const float u = w1[a] * xm + b1[a];
        const float g = (u > 0.f) ? 1.f : 0.f;
        alpha += g * w1[a] * w2[a * 16 + c];
        beta  += g * b1[a] * w2[a * 16 + c];
      }
      if (alpha != 0.f) {
        const float z = -beta / alpha;
        if (z > lo && z < hi) { int p = atomicAdd(&nks, 1); allk[p] = z; }
      }
    }
  }
  if (t < n1) { int p = atomicAdd(&nks, 1); allk[p] = k1[t]; }
  __syncthreads();
  const int nk = nks;

  // Step 3: rank sort (<=288 elements).
  for (int x = t; x < nk; x += 64) {
    const float v = allk[x];
    int r = 0;
    for (int y = 0; y < nk; ++y) {
      const float u = allk[y];
      r += (u < v) || (u == v && y < x);
    }
    skn[r] = v;
  }
  __syncthreads();

  // Step 4: per-segment exact linear form for all 8 heads.
  for (int s = t; s <= nk; s += 64) {
    float xm;
    if (nk == 0) xm = 0.f;
    else if (s == 0) xm = skn[0] - 1.f;
    else if (s == nk) xm = skn[nk - 1] + 1.f;
    else xm = 0.5f * (skn[s - 1] + skn[s]);
    float alpha[16], beta[16];
#pragma unroll
    for (int c = 0; c < 16; ++c) {
      float al = 0.f, be = b2[c];
#pragma unroll
      for (int a = 0; a < 16; ++a) {
        const float u = w1[a] * xm + b1[a];
        const float g = (u > 0.f) ? 1.f : 0.f;
        al += g * w1[a] * w2[a * 16 + c];
        be += g * b1[a] * w2[a * 16 + c];
      }
      alpha[c] = al; beta[c] = be;
    }
    float Ah[8], Bh[8];
#pragma unroll
    for (int h = 0; h < 8; ++h) { Ah[h] = 0.f; Bh[h] = b3[h]; }
#pragma unroll
    for (int c = 0; c < 16; ++c) {
      const float argc = alpha[c] * xm + beta[c];
      if (argc > 0.f) {
#pragma unroll
        for (int h = 0; h < 8; ++h) {
          Ah[h] += alpha[c] * w3[c * 8 + h];
          Bh[h] += beta[c]  * w3[c * 8 + h];
        }
      }
    }
#pragma unroll
    for (int h = 0; h < 8; ++h) {
      tab_out[s * 16 + h]     = Ah[h];
      tab_out[s * 16 + 8 + h] = Bh[h];
    }
  }
  for (int x = t; x < nk; x += 64) knots_out[x] = skn[x];
  // LUT: lut[bin] = #knots < left edge of bin (lower bound for segment idx).
  for (int bin = t; bin < LUTN; bin += 64) {
    const float x0 = LUT_LO + (float)bin / LUT_SCALE;
    int l = 0, h2 = nk;
    while (l < h2) { const int mid = (l + h2) >> 1;
      if (skn[mid] < x0) l = mid + 1; else h2 = mid; }
    lut_out[bin] = l;
  }
  if (t == 0) nk_out[0] = nk;
}

// ---------------------------------------------------------------------------
// Kernel 1: Q/K/V projections (unchanged). grid (64, 8), block 256.
// ---------------------------------------------------------------------------
__global__ __launch_bounds__(256) void qkv_kernel(
    const float* __restrict__ qin, const float* __restrict__ hin,
    const float* __restrict__ Wq, const float* __restrict__ Wk,
    const float* __restrict__ Wv, float* __restrict__ Q,
    float* __restrict__ K, float* __restrict__ V) {
  const int lin = blockIdx.y * 64 + blockIdx.x;
  const int swz = (lin & 7) * 64 + (lin >> 3);
  const int hd = swz & 7;
  const int xb = swz >> 3;
  const int r0 = xb * 512 + threadIdx.x;
  __shared__ __align__(16) float wt[3][16][128];

  {
    const float* W;
#pragma unroll
    for (int m = 0; m < 3; ++m) {
      W = (m == 0) ? Wq : (m == 1) ? Wk : Wv;
      for (int idx = threadIdx.x; idx < 2048; idx += 256) {
        const int d = idx >> 4, k = idx & 15;
        wt[m][k][d] = W[hd * 2048 + idx];
      }
    }
  }
  __syncthreads();

  for (int m = 0; m < 3; ++m) {
    const float* src = (m == 0) ? qin : hin;
    float acc0[16], acc1[16];
#pragma unroll
    for (int k = 0; k < 16; ++k) { acc0[k] = 0.f; acc1[k] = 0.f; }
    const float4* row0 = reinterpret_cast<const float4*>(src + (size_t)r0 * DIN);
    const float4* row1 = reinterpret_cast<const float4*>(src + (size_t)(r0 + 256) * DIN);
    for (int d4 = 0; d4 < 32; ++d4) {
      const float4 c0 = row0[d4];
      const float4 c1 = row1[d4];
#pragma unroll
      for (int k = 0; k < 16; ++k) {
        const float4 w = *reinterpret_cast<const float4*>(&wt[m][k][d4 * 4]);
        acc0[k] += c0.x * w.x + c0.y * w.y + c0.z * w.z + c0.w * w.w;
        acc1[k] += c1.x * w.x + c1.y * w.y + c1.z * w.z + c1.w * w.w;
      }
    }
    const float scale = (m == 0) ? NORMC : 1.f;
    float* dst = (m == 0) ? Q : (m == 1) ? K : V;
    float4* o0 = reinterpret_cast<float4*>(dst + ((size_t)hd * B_ * N_ + r0) * DK);
    float4* o1 = reinterpret_cast<float4*>(dst + ((size_t)hd * B_ * N_ + r0 + 256) * DK);
#pragma unroll
    for (int kq = 0; kq < 4; ++kq) {
      o0[kq] = make_float4(acc0[kq*4+0]*scale, acc0[kq*4+1]*scale,
                           acc0[kq*4+2]*scale, acc0[kq*4+3]*scale);
      o1[kq] = make_float4(acc1[kq*4+0]*scale, acc1[kq*4+1]*scale,
                           acc1[kq*4+2]*scale, acc1[kq*4+3]*scale);
    }
  }
}

// ---------------------------------------------------------------------------
// Kernel 2: fused bias-LUT + masked softmax attention + output projection.
// grid = B*N blocks, block = 256 (thread = key j). 6 barrier phases.
// ---------------------------------------------------------------------------
__global__ __launch_bounds__(256) void attn_kernel(
    const float* __restrict__ Q, const float* __restrict__ K,
    const float* __restrict__ V, const int* __restrict__ mask,
    const float* __restrict__ edge, const float* __restrict__ knots_g,
    const float* __restrict__ tab_g, const int* __restrict__ nk_g,
    const int* __restrict__ lut_g, const float* __restrict__ Wo,
    float* __restrict__ out) {
  const int t = threadIdx.x;
  const int lin = blockIdx.x;
  const int swz = (lin & 7) * 4096 + (lin >> 3);  // bijective: 32768 = 8*4096
  const int b = swz >> 8;
  const int i = swz & 255;

  __shared__ float skn[MAXSEG];
  __shared__ unsigned short slut[LUTN];
  __shared__ __align__(16) float qi[H_ * DK];
  __shared__ __align__(16) float P[H_][PADN];
  __shared__ float sumrcp[H_];
  __shared__ __align__(16) float4 part[H_][4][8];
  __shared__ __align__(16) float heads[H_ * DV];
  __shared__ float opart[256];

  const int NK = nk_g[0];
  for (int x = t; x < NK; x += 256) skn[x] = knots_g[x];
  for (int x = t; x < LUTN; x += 256) slut[x] = (unsigned short)lut_g[x];
  if (t < H_ * DK)
    qi[t] = Q[((size_t)(t >> 4) * B_ * N_ + (size_t)b * N_ + i) * DK + (t & 15)];
  __syncthreads();  // --- A: staging done

  // ---- Phase 1: bias lookup + QK score, key j = t --------------------------
  const int j = t;
  const size_t rowij = (size_t)(b * N_ + i) * N_ + j;
  const int mv = mask[rowij];
  const float e = edge[rowij];

  int seg;
  if (e < LUT_LO) {  // cold exact path (never for N(0,1) data)
    int l = 0, h2 = NK;
    while (l < h2) {
      const int mid = (l + h2) >> 1;
      const bool lt = skn[mid] < e;
      l = lt ? mid + 1 : l;
      h2 = lt ? h2 : mid;
    }
    seg = l;
  } else {
    int bin = (int)((e - LUT_LO) * LUT_SCALE);
    bin = bin > (LUTN - 1) ? (LUTN - 1) : bin;
    seg = slut[bin];
    while (seg < NK && skn[seg] < e) ++seg;  // avg <1 step
  }
  const float4* tg4 = reinterpret_cast<const float4*>(tab_g) + (size_t)seg * 4;
  const float4 ta = tg4[0], tb = tg4[1], tc = tg4[2], td = tg4[3];
  float s[H_];
  s[0] = fmaf(ta.x, e, tc.x); s[1] = fmaf(ta.y, e, tc.y);
  s[2] = fmaf(ta.z, e, tc.z); s[3] = fmaf(ta.w, e, tc.w);
  s[4] = fmaf(tb.x, e, td.x); s[5] = fmaf(tb.y, e, td.y);
  s[6] = fmaf(tb.z, e, td.z); s[7] = fmaf(tb.w, e, td.w);

  const float4* Kp = reinterpret_cast<const float4*>(K);
  const float4* qi4 = reinterpret_cast<const float4*>(qi);
#pragma unroll
  for (int hh = 0; hh < H_; ++hh) {
    const size_t kb = ((size_t)hh * B_ * N_ + (size_t)b * N_ + j) * (DK / 4);
    const float4 k0 = Kp[kb + 0], k1 = Kp[kb + 1], k2 = Kp[kb + 2], k3 = Kp[kb + 3];
    const float4 q0 = qi4[hh * 4 + 0], q1 = qi4[hh * 4 + 1];
    const float4 q2 = qi4[hh * 4 + 2], q3 = qi4[hh * 4 + 3];
    const float dot =
        q0.x * k0.x + q0.y * k0.y + q0.z * k0.z + q0.w * k0.w +
        q1.x * k1.x + q1.y * k1.y + q1.z * k1.z + q1.w * k1.w +
        q2.x * k2.x + q2.y * k2.y + q2.z * k2.z + q2.w * k2.w +
        q3.x * k3.x + q3.y * k3.y + q3.z * k3.z + q3.w * k3.w;
    s[hh] += dot;
    if (mv) s[hh] = -INFINITY;
  }
#pragma unroll
  for (int hh = 0; hh < H_; ++hh) P[hh][j] = s[hh];
  __syncthreads();  // --- B: raw scores in LDS

  // ---- Coop softmax: 32 threads per head; one barrier phase ----------------
  {
    const int h = t >> 5, c = t & 31;
    float* row = &P[h][c * 8];
    const float4 v0 = *reinterpret_cast<const float4*>(row);
    const float4 v1 = *reinterpret_cast<const float4*>(row + 4);
    float M = fmaxf(fmaxf(fmaxf(v0.x, v0.y), fmaxf(v0.z, v0.w)),
                    fmaxf(fmaxf(v1.x, v1.y), fmaxf(v1.z, v1.w)));
#pragma unroll
    for (int off = 1; off < 32; off <<= 1) M = fmaxf(M, __shfl_xor(M, off, 32));
    const float e0 = (v0.x == -INFINITY) ? 0.f : __expf(v0.x - M);
    const float e1 = (v0.y == -INFINITY) ? 0.f : __expf(v0.y - M);
    const float e2 = (v0.z == -INFINITY) ? 0.f : __expf(v0.z - M);
    const float e3 = (v0.w == -INFINITY) ? 0.f : __expf(v0.w - M);
    const float e4 = (v1.x == -INFINITY) ? 0.f : __expf(v1.x - M);
    const float e5 = (v1.y == -INFINITY) ? 0.f : __expf(v1.y - M);
    const float e6 = (v1.z == -INFINITY) ? 0.f : __expf(v1.z - M);
    const float e7 = (v1.w == -INFINITY) ? 0.f : __expf(v1.w - M);
    *reinterpret_cast<float4*>(row)     = make_float4(e0, e1, e2, e3);
    *reinterpret_cast<float4*>(row + 4) = make_float4(e4, e5, e6, e7);
    float S = (e0 + e1) + (e2 + e3) + (e4 + e5) + (e6 + e7);
#pragma unroll
    for (int off = 1; off < 32; off <<= 1) S += __shfl_xor(S, off, 32);
    if (c == 0) sumrcp[h] = (S > 0.f) ? 1.f / S : 0.f;
  }
  __syncthreads();  // --- C: P = unnormalized probs, sumrcp ready

  // ---- Phase 2: heads[h,:] = rs * sum_j P[h,j] * V[h,b,j,:] ----------------
  {
    const int h2 = t >> 5;
    const int g = t & 31;
    const int v4 = g & 3;
    const int jsl = g >> 2;
    const float4* Vp = reinterpret_cast<const float4*>(V);
    const size_t vbase = ((size_t)h2 * B_ * N_ + (size_t)b * N_) * 4;
    float4 acc = make_float4(0.f, 0.f, 0.f, 0.f);
    for (int jj = 0; jj < 32; ++jj) {
      const int jx = jj * 8 + jsl;
      const float pj = P[h2][jx];
      const float4 vv = Vp[vbase + (size_t)jx * 4 + v4];
      acc.x = fmaf(pj, vv.x, acc.x);
      acc.y = fmaf(pj, vv.y, acc.y);
      acc.z = fmaf(pj, vv.z, acc.z);
      acc.w = fmaf(pj, vv.w, acc.w);
    }
    part[h2][v4][jsl] = acc;
  }
  __syncthreads();  // --- D
  if (t < 32) {
    const int hh = t >> 2, vq = t & 3;
    float4 sacc = part[hh][vq][0];
#pragma unroll
    for (int r = 1; r < 8; ++r) {
      const float4 pz = part[hh][vq][r];
      sacc.x += pz.x; sacc.y += pz.y; sacc.z += pz.z; sacc.w += pz.w;
    }
    const float rs = sumrcp[hh];
    heads[hh * DV + vq * 4 + 0] = sacc.x * rs;
    heads[hh * DV + vq * 4 + 1] = sacc.y * rs;
    heads[hh * DV + vq * 4 + 2] = sacc.z * rs;
    heads[hh * DV + vq * 4 + 3] = sacc.w * rs;
  }
  __syncthreads();  // --- E

  // ---- Phase 3: out[b,i,e] = sum_{hv} heads[hv] * Wo[hv,e], split 2-way ----
  {
    const int e_ = t & 127, half = t >> 7;
    const float4* h4 = reinterpret_cast<const float4*>(heads);
    float acc = 0.f;
#pragma unroll
    for (int hq = 0; hq < 16; ++hq) {
      const int hqq = half * 16 + hq;
      const float4 hv = h4[hqq];
      acc = fmaf(hv.x, Wo[(hqq * 4 + 0) * DE + e_], acc);
      acc = fmaf(hv.y, Wo[(hqq * 4 + 1) * DE + e_], acc);
      acc = fmaf(hv.z, Wo[(hqq * 4 + 2) * DE + e_], acc);
      acc = fmaf(hv.w, Wo[(hqq * 4 + 3) * DE + e_], acc);
    }
    opart[t] = acc;
  }
  __syncthreads();  // --- F
  if (t < DE)
    out[((size_t)(b * N_ + i)) * DE + t] = opart[t] + opart[t + 128];
}

extern "C" void kernel_launch(void* const* d_in, const int* in_sizes, int n_in,
                              void* d_out, int out_size, void* d_ws, size_t ws_size,
                              hipStream_t stream) {
  const float* q    = (const float*)d_in[0];
  const float* hm   = (const float*)d_in[1];
  const int* mask   = (const int*)d_in[2];
  const float* edge = (const float*)d_in[3];
  const float* Wq   = (const float*)d_in[4];
  const float* Wk   = (const float*)d_in[5];
  const float* Wv   = (const float*)d_in[6];
  const float* Wo   = (const float*)d_in[7];
  const float* mw1  = (const float*)d_in[8];
  const float* mb1  = (const float*)d_in[9];
  const float* mw2  = (const float*)d_in[10];
  const float* mb2  = (const float*)d_in[11];
  const float* mw3  = (const float*)d_in[12];
  const float* mb3  = (const float*)d_in[13];
  float* out = (float*)d_out;

  float* ws = (float*)d_ws;
  const size_t per = (size_t)H_ * B_ * N_ * DK;  // 4,194,304 floats
  float* Q = ws;
  float* K = ws + per;
  float* V = ws + 2 * per;
  float* knots = ws + 3 * per;          // 512 slots
  float* tab   = knots + 512;           // MAXSEG*16 <= 4864 -> 8192 slots
  int*   nk    = (int*)(tab + 8192);
  int*   lut   = nk + 16;               // LUTN ints

  edge_precompute<<<1, 64, 0, stream>>>(mw1, mb1, mw2, mb2, mw3, mb3,
                                        knots, tab, nk, lut);
  qkv_kernel<<<dim3(B_ * N_ / 512, H_), 256, 0, stream>>>(q, hm, Wq, Wk, Wv, Q, K, V);
  attn_kernel<<<dim3(B_ * N_), 256, 0, stream>>>(Q, K, V, mask, edge, knots, tab,
                                                 nk, lut, Wo, out);
}

// Round 10
// 516.935 us; speedup vs baseline: 3.8430x; 1.6531x over previous
//
#include <hip/hip_runtime.h>
#include <math.h>

#define H_   8
#define DIN  128
#define DK   16
#define DV   16
#define DE   128
#define B_   128
#define N_   256
#define NORMC 0.25f
#define MAXSEG 304
#define LUTN 2048
#define LUT_LO (-16.0f)
#define LUT_SCALE 64.0f
#define PADN 260
#define QB   4     // queries per block

// ---------------------------------------------------------------------------
// Kernel 0: edge-MLP -> exact piecewise-linear table + bin->segment LUT.
// ---------------------------------------------------------------------------
__global__ void edge_precompute(
    const float* __restrict__ mw1, const float* __restrict__ mb1,
    const float* __restrict__ mw2, const float* __restrict__ mb2,
    const float* __restrict__ mw3, const float* __restrict__ mb3,
    float* __restrict__ knots_out, float* __restrict__ tab_out,
    int* __restrict__ nk_out, int* __restrict__ lut_out) {
  const int t = threadIdx.x;  // 64 threads
  __shared__ float w1[16], b1[16], w2[256], b2[16], w3[128], b3[8];
  __shared__ float k1[16];
  __shared__ float allk[MAXSEG];
  __shared__ float skn[MAXSEG];
  __shared__ int n1s, nks;

  if (t < 16) { w1[t] = mw1[t]; b1[t] = mb1[t]; b2[t] = mb2[t]; }
  if (t < 8) b3[t] = mb3[t];
  for (int x = t; x < 256; x += 64) w2[x] = mw2[x];
  for (int x = t; x < 128; x += 64) w3[x] = mw3[x];
  __syncthreads();

  if (t == 0) {
    int n = 0;
    for (int a = 0; a < 16; ++a)
      if (w1[a] != 0.f) k1[n++] = -b1[a] / w1[a];
    for (int x = 1; x < n; ++x) {
      float v = k1[x]; int y = x - 1;
      while (y >= 0 && k1[y] > v) { k1[y + 1] = k1[y]; --y; }
      k1[y + 1] = v;
    }
    n1s = n; nks = 0;
  }
  __syncthreads();
  const int n1 = n1s;

  if (t <= n1) {
    const float lo = (t == 0) ? -INFINITY : k1[t - 1];
    const float hi = (t == n1) ? INFINITY : k1[t];
    float xm;
    if (n1 == 0) xm = 0.f;
    else if (t == 0) xm = k1[0] - 1.f;
    else if (t == n1) xm = k1[n1 - 1] + 1.f;
    else xm = 0.5f * (lo + hi);
#pragma unroll
    for (int c = 0; c < 16; ++c) {
      float alpha = 0.f, beta = b2[c];
#pragma unroll
      for (int a = 0; a < 16; ++a) {
        const float u = w1[a] * xm + b1[a];
        const float g = (u > 0.f) ? 1.f : 0.f;
        alpha += g * w1[a] * w2[a * 16 + c];
        beta  += g * b1[a] * w2[a * 16 + c];
      }
      if (alpha != 0.f) {
        const float z = -beta / alpha;
        if (z > lo && z < hi) { int p = atomicAdd(&nks, 1); allk[p] = z; }
      }
    }
  }
  if (t < n1) { int p = atomicAdd(&nks, 1); allk[p] = k1[t]; }
  __syncthreads();
  const int nk = nks;

  for (int x = t; x < nk; x += 64) {
    const float v = allk[x];
    int r = 0;
    for (int y = 0; y < nk; ++y) {
      const float u = allk[y];
      r += (u < v) || (u == v && y < x);
    }
    skn[r] = v;
  }
  __syncthreads();

  for (int s = t; s <= nk; s += 64) {
    float xm;
    if (nk == 0) xm = 0.f;
    else if (s == 0) xm = skn[0] - 1.f;
    else if (s == nk) xm = skn[nk - 1] + 1.f;
    else xm = 0.5f * (skn[s - 1] + skn[s]);
    float alpha[16], beta[16];
#pragma unroll
    for (int c = 0; c < 16; ++c) {
      float al = 0.f, be = b2[c];
#pragma unroll
      for (int a = 0; a < 16; ++a) {
        const float u = w1[a] * xm + b1[a];
        const float g = (u > 0.f) ? 1.f : 0.f;
        al += g * w1[a] * w2[a * 16 + c];
        be += g * b1[a] * w2[a * 16 + c];
      }
      alpha[c] = al; beta[c] = be;
    }
    float Ah[8], Bh[8];
#pragma unroll
    for (int h = 0; h < 8; ++h) { Ah[h] = 0.f; Bh[h] = b3[h]; }
#pragma unroll
    for (int c = 0; c < 16; ++c) {
      const float argc = alpha[c] * xm + beta[c];
      if (argc > 0.f) {
#pragma unroll
        for (int h = 0; h < 8; ++h) {
          Ah[h] += alpha[c] * w3[c * 8 + h];
          Bh[h] += beta[c]  * w3[c * 8 + h];
        }
      }
    }
#pragma unroll
    for (int h = 0; h < 8; ++h) {
      tab_out[s * 16 + h]     = Ah[h];
      tab_out[s * 16 + 8 + h] = Bh[h];
    }
  }
  for (int x = t; x < nk; x += 64) knots_out[x] = skn[x];
  for (int bin = t; bin < LUTN; bin += 64) {
    const float x0 = LUT_LO + (float)bin / LUT_SCALE;
    int l = 0, h2 = nk;
    while (l < h2) { const int mid = (l + h2) >> 1;
      if (skn[mid] < x0) l = mid + 1; else h2 = mid; }
    lut_out[bin] = l;
  }
  if (t == 0) nk_out[0] = nk;
}

// ---------------------------------------------------------------------------
// Kernel 1: Q/K/V projections (unchanged).
// ---------------------------------------------------------------------------
__global__ __launch_bounds__(256) void qkv_kernel(
    const float* __restrict__ qin, const float* __restrict__ hin,
    const float* __restrict__ Wq, const float* __restrict__ Wk,
    const float* __restrict__ Wv, float* __restrict__ Q,
    float* __restrict__ K, float* __restrict__ V) {
  const int lin = blockIdx.y * 64 + blockIdx.x;
  const int swz = (lin & 7) * 64 + (lin >> 3);
  const int hd = swz & 7;
  const int xb = swz >> 3;
  const int r0 = xb * 512 + threadIdx.x;
  __shared__ __align__(16) float wt[3][16][128];

  {
    const float* W;
#pragma unroll
    for (int m = 0; m < 3; ++m) {
      W = (m == 0) ? Wq : (m == 1) ? Wk : Wv;
      for (int idx = threadIdx.x; idx < 2048; idx += 256) {
        const int d = idx >> 4, k = idx & 15;
        wt[m][k][d] = W[hd * 2048 + idx];
      }
    }
  }
  __syncthreads();

  for (int m = 0; m < 3; ++m) {
    const float* src = (m == 0) ? qin : hin;
    float acc0[16], acc1[16];
#pragma unroll
    for (int k = 0; k < 16; ++k) { acc0[k] = 0.f; acc1[k] = 0.f; }
    const float4* row0 = reinterpret_cast<const float4*>(src + (size_t)r0 * DIN);
    const float4* row1 = reinterpret_cast<const float4*>(src + (size_t)(r0 + 256) * DIN);
    for (int d4 = 0; d4 < 32; ++d4) {
      const float4 c0 = row0[d4];
      const float4 c1 = row1[d4];
#pragma unroll
      for (int k = 0; k < 16; ++k) {
        const float4 w = *reinterpret_cast<const float4*>(&wt[m][k][d4 * 4]);
        acc0[k] += c0.x * w.x + c0.y * w.y + c0.z * w.z + c0.w * w.w;
        acc1[k] += c1.x * w.x + c1.y * w.y + c1.z * w.z + c1.w * w.w;
      }
    }
    const float scale = (m == 0) ? NORMC : 1.f;
    float* dst = (m == 0) ? Q : (m == 1) ? K : V;
    float4* o0 = reinterpret_cast<float4*>(dst + ((size_t)hd * B_ * N_ + r0) * DK);
    float4* o1 = reinterpret_cast<float4*>(dst + ((size_t)hd * B_ * N_ + r0 + 256) * DK);
#pragma unroll
    for (int kq = 0; kq < 4; ++kq) {
      o0[kq] = make_float4(acc0[kq*4+0]*scale, acc0[kq*4+1]*scale,
                           acc0[kq*4+2]*scale, acc0[kq*4+3]*scale);
      o1[kq] = make_float4(acc1[kq*4+0]*scale, acc1[kq*4+1]*scale,
                           acc1[kq*4+2]*scale, acc1[kq*4+3]*scale);
    }
  }
}

// ---------------------------------------------------------------------------
// Kernel 2: QB=4 queries per block. grid = B*N/QB = 8192 blocks, 256 threads
// (thread = key j). K/V/Wo loads amortized 4x. LUT/knots read from global L2.
// ---------------------------------------------------------------------------
__global__ __launch_bounds__(256) void attn_kernel(
    const float* __restrict__ Q, const float* __restrict__ K,
    const float* __restrict__ V, const int* __restrict__ mask,
    const float* __restrict__ edge, const float* __restrict__ knots_g,
    const float* __restrict__ tab_g, const int* __restrict__ nk_g,
    const int* __restrict__ lut_g, const float* __restrict__ Wo,
    float* __restrict__ out) {
  const int t = threadIdx.x;
  const int lin = blockIdx.x;
  const int swz = (lin & 7) * 1024 + (lin >> 3);  // bijective: 8192 = 8*1024
  const int b = swz >> 6;
  const int i0 = (swz & 63) << 2;                 // queries i0..i0+3

  __shared__ __align__(16) float qi[QB][H_ * DK];
  __shared__ __align__(16) float P[QB][H_][PADN];
  __shared__ float sumrcp[QB][H_];
  __shared__ __align__(16) float heads[QB][H_ * DV];

  const int NK = nk_g[0];
  // stage 4 queries' Q rows (512 floats)
  for (int x = t; x < QB * H_ * DK; x += 256) {
    const int qq = x >> 7, rem = x & 127;  // rem = h*16+k
    qi[qq][rem] = Q[((size_t)(rem >> 4) * B_ * N_ + (size_t)b * N_ + (i0 + qq)) * DK
                    + (rem & 15)];
  }
  __syncthreads();  // --- A

  // ---- Phase 1: bias lookup + QK for 4 queries, key j = t ------------------
  const int j = t;
  float s[QB][H_];
  int mv[QB];
#pragma unroll
  for (int qq = 0; qq < QB; ++qq) {
    const size_t rowij = (size_t)(b * N_ + i0 + qq) * N_ + j;
    mv[qq] = mask[rowij];
    const float e = edge[rowij];
    int seg;
    if (e < LUT_LO) {
      int l = 0, h2 = NK;
      while (l < h2) {
        const int mid = (l + h2) >> 1;
        const bool lt = knots_g[mid] < e;
        l = lt ? mid + 1 : l;
        h2 = lt ? h2 : mid;
      }
      seg = l;
    } else {
      int bin = (int)((e - LUT_LO) * LUT_SCALE);
      bin = bin > (LUTN - 1) ? (LUTN - 1) : bin;
      seg = lut_g[bin];
      while (seg < NK && knots_g[seg] < e) ++seg;
    }
    const float4* tg4 = reinterpret_cast<const float4*>(tab_g) + (size_t)seg * 4;
    const float4 ta = tg4[0], tb = tg4[1], tc = tg4[2], td = tg4[3];
    s[qq][0] = fmaf(ta.x, e, tc.x); s[qq][1] = fmaf(ta.y, e, tc.y);
    s[qq][2] = fmaf(ta.z, e, tc.z); s[qq][3] = fmaf(ta.w, e, tc.w);
    s[qq][4] = fmaf(tb.x, e, td.x); s[qq][5] = fmaf(tb.y, e, td.y);
    s[qq][6] = fmaf(tb.z, e, td.z); s[qq][7] = fmaf(tb.w, e, td.w);
  }

  const float4* Kp = reinterpret_cast<const float4*>(K);
#pragma unroll
  for (int hh = 0; hh < H_; ++hh) {
    const size_t kb = ((size_t)hh * B_ * N_ + (size_t)b * N_ + j) * (DK / 4);
    const float4 k0 = Kp[kb + 0], k1 = Kp[kb + 1], k2 = Kp[kb + 2], k3 = Kp[kb + 3];
#pragma unroll
    for (int qq = 0; qq < QB; ++qq) {
      const float4* q4 = reinterpret_cast<const float4*>(&qi[qq][hh * DK]);
      const float4 q0 = q4[0], q1 = q4[1], q2 = q4[2], q3 = q4[3];
      const float dot =
          q0.x * k0.x + q0.y * k0.y + q0.z * k0.z + q0.w * k0.w +
          q1.x * k1.x + q1.y * k1.y + q1.z * k1.z + q1.w * k1.w +
          q2.x * k2.x + q2.y * k2.y + q2.z * k2.z + q2.w * k2.w +
          q3.x * k3.x + q3.y * k3.y + q3.z * k3.z + q3.w * k3.w;
      s[qq][hh] = mv[qq] ? -INFINITY : (s[qq][hh] + dot);
    }
  }
#pragma unroll
  for (int qq = 0; qq < QB; ++qq)
#pragma unroll
    for (int hh = 0; hh < H_; ++hh) P[qq][hh][j] = s[qq][hh];
  __syncthreads();  // --- B: raw scores in LDS

  // ---- Coop softmax: 32 rows (qq,h) x 8 threads; rotated chunk order -------
  {
    const int row = t >> 3, c = t & 7;        // row = qq*8+h
    const int qq = row >> 3, h = row & 7;
    float4* r4 = reinterpret_cast<float4*>(&P[qq][h][0]) + c * 8;
    float4 v[8];
#pragma unroll
    for (int k = 0; k < 8; ++k) v[k] = r4[(c + k) & 7];
    float M = -INFINITY;
#pragma unroll
    for (int k = 0; k < 8; ++k)
      M = fmaxf(M, fmaxf(fmaxf(v[k].x, v[k].y), fmaxf(v[k].z, v[k].w)));
#pragma unroll
    for (int off = 1; off < 8; off <<= 1) M = fmaxf(M, __shfl_xor(M, off, 64));
    float S = 0.f;
#pragma unroll
    for (int k = 0; k < 8; ++k) {
      v[k].x = (v[k].x == -INFINITY) ? 0.f : __expf(v[k].x - M);
      v[k].y = (v[k].y == -INFINITY) ? 0.f : __expf(v[k].y - M);
      v[k].z = (v[k].z == -INFINITY) ? 0.f : __expf(v[k].z - M);
      v[k].w = (v[k].w == -INFINITY) ? 0.f : __expf(v[k].w - M);
      S += (v[k].x + v[k].y) + (v[k].z + v[k].w);
    }
#pragma unroll
    for (int k = 0; k < 8; ++k) r4[(c + k) & 7] = v[k];
#pragma unroll
    for (int off = 1; off < 8; off <<= 1) S += __shfl_xor(S, off, 64);
    if (c == 0) sumrcp[qq][h] = (S > 0.f) ? 1.f / S : 0.f;
  }
  __syncthreads();  // --- C

  // ---- Phase 2: PV for 4 queries; V load amortized; shuffle-reduce ---------
  {
    const int h2 = t >> 5;
    const int g = t & 31;
    const int v4 = g & 3;
    const int jsl = g >> 2;
    const float4* Vp = reinterpret_cast<const float4*>(V);
    const size_t vbase = ((size_t)h2 * B_ * N_ + (size_t)b * N_) * 4;
    float4 acc[QB];
#pragma unroll
    for (int qq = 0; qq < QB; ++qq) acc[qq] = make_float4(0.f, 0.f, 0.f, 0.f);
    for (int jj = 0; jj < 32; ++jj) {
      const int jx = jj * 8 + jsl;
      const float4 vv = Vp[vbase + (size_t)jx * 4 + v4];
#pragma unroll
      for (int qq = 0; qq < QB; ++qq) {
        const float pj = P[qq][h2][jx];
        acc[qq].x = fmaf(pj, vv.x, acc[qq].x);
        acc[qq].y = fmaf(pj, vv.y, acc[qq].y);
        acc[qq].z = fmaf(pj, vv.z, acc[qq].z);
        acc[qq].w = fmaf(pj, vv.w, acc[qq].w);
      }
    }
    // reduce over jsl (8 lanes apart by 4) via xor-shuffles
#pragma unroll
    for (int off = 4; off < 32; off <<= 1) {
#pragma unroll
      for (int qq = 0; qq < QB; ++qq) {
        acc[qq].x += __shfl_xor(acc[qq].x, off, 64);
        acc[qq].y += __shfl_xor(acc[qq].y, off, 64);
        acc[qq].z += __shfl_xor(acc[qq].z, off, 64);
        acc[qq].w += __shfl_xor(acc[qq].w, off, 64);
      }
    }
    if (jsl == 0) {
#pragma unroll
      for (int qq = 0; qq < QB; ++qq) {
        const float rs = sumrcp[qq][h2];
        float* hd = &heads[qq][h2 * DV + v4 * 4];
        hd[0] = acc[qq].x * rs; hd[1] = acc[qq].y * rs;
        hd[2] = acc[qq].z * rs; hd[3] = acc[qq].w * rs;
      }
    }
  }
  __syncthreads();  // --- D

  // ---- Phase 3: out[b,i0+qq,e]; each thread does 2 qq sharing Wo loads -----
  {
    const int e_ = t & 127, qq0 = t >> 7;   // qq in {qq0, qq0+2}
    const float4* h4a = reinterpret_cast<const float4*>(&heads[qq0][0]);
    const float4* h4b = reinterpret_cast<const float4*>(&heads[qq0 + 2][0]);
    float acca = 0.f, accb = 0.f;
#pragma unroll
    for (int hq = 0; hq < 32; ++hq) {
      const float4 ha = h4a[hq];
      const float4 hb = h4b[hq];
      const float w0 = Wo[(hq * 4 + 0) * DE + e_];
      const float w1 = Wo[(hq * 4 + 1) * DE + e_];
      const float w2 = Wo[(hq * 4 + 2) * DE + e_];
      const float w3 = Wo[(hq * 4 + 3) * DE + e_];
      acca = fmaf(ha.x, w0, fmaf(ha.y, w1, fmaf(ha.z, w2, fmaf(ha.w, w3, acca))));
      accb = fmaf(hb.x, w0, fmaf(hb.y, w1, fmaf(hb.z, w2, fmaf(hb.w, w3, accb))));
    }
    out[((size_t)(b * N_ + i0 + qq0)) * DE + e_] = acca;
    out[((size_t)(b * N_ + i0 + qq0 + 2)) * DE + e_] = accb;
  }
}

extern "C" void kernel_launch(void* const* d_in, const int* in_sizes, int n_in,
                              void* d_out, int out_size, void* d_ws, size_t ws_size,
                              hipStream_t stream) {
  const float* q    = (const float*)d_in[0];
  const float* hm   = (const float*)d_in[1];
  const int* mask   = (const int*)d_in[2];
  const float* edge = (const float*)d_in[3];
  const float* Wq   = (const float*)d_in[4];
  const float* Wk   = (const float*)d_in[5];
  const float* Wv   = (const float*)d_in[6];
  const float* Wo   = (const float*)d_in[7];
  const float* mw1  = (const float*)d_in[8];
  const float* mb1  = (const float*)d_in[9];
  const float* mw2  = (const float*)d_in[10];
  const float* mb2  = (const float*)d_in[11];
  const float* mw3  = (const float*)d_in[12];
  const float* mb3  = (const float*)d_in[13];
  float* out = (float*)d_out;

  float* ws = (float*)d_ws;
  const size_t per = (size_t)H_ * B_ * N_ * DK;  // 4,194,304 floats
  float* Q = ws;
  float* K = ws + per;
  float* V = ws + 2 * per;
  float* knots = ws + 3 * per;          // 512 slots
  float* tab   = knots + 512;           // 8192 slots
  int*   nk    = (int*)(tab + 8192);
  int*   lut   = nk + 16;               // LUTN ints

  edge_precompute<<<1, 64, 0, stream>>>(mw1, mb1, mw2, mb2, mw3, mb3,
                                        knots, tab, nk, lut);
  qkv_kernel<<<dim3(B_ * N_ / 512, H_), 256, 0, stream>>>(q, hm, Wq, Wk, Wv, Q, K, V);
  attn_kernel<<<dim3(B_ * N_ / QB), 256, 0, stream>>>(Q, K, V, mask, edge, knots,
                                                      tab, nk, lut, Wo, out);
}